// Round 6
// baseline (184.590 us; speedup 1.0000x reference)
//
#include <hip/hip_runtime.h>
#include <hip/hip_bf16.h>
#include <math.h>

#define Bn 4
#define Cn 128
#define Hn 128
#define Wn 128
#define COn 128
#define HWn (Hn*Wn)        // 16384
#define NPIX (Bn*HWn)      // 65536

typedef __attribute__((ext_vector_type(8))) short bf16x8;
typedef __attribute__((ext_vector_type(4))) float f32x4;

__device__ inline unsigned short f2bf_hw(float f) {
    __hip_bfloat16 h = __float2bfloat16(f);     // HW cvt (RNE)
    return *reinterpret_cast<unsigned short*>(&h);
}
__device__ inline unsigned pack_bf2(float lo, float hi) {
    __hip_bfloat162 h2;
    h2.x = __float2bfloat16(lo);
    h2.y = __float2bfloat16(hi);                // fuses to v_cvt_pk_bf16_f32
    return *reinterpret_cast<unsigned*>(&h2);
}
__device__ inline float bflo(unsigned w) {
    union { unsigned u; float f; } cv; cv.u = w << 16; return cv.f;
}
__device__ inline float bfhi(unsigned w) {
    union { unsigned u; float f; } cv; cv.u = w & 0xffff0000u; return cv.f;
}
__device__ inline void async_copy16(const void* g, void* l) {
    __builtin_amdgcn_global_load_lds(
        (const __attribute__((address_space(1))) unsigned int*)g,
        (__attribute__((address_space(3))) unsigned int*)l, 16, 0, 0);
}

// ---------------------------------------------------------------------------
// Kernel 1: NCHW f32 -> NHWC bf16 transpose. Block = one (b,h) row.
// ---------------------------------------------------------------------------
__global__ __launch_bounds__(256) void k_transpose(
    const float* __restrict__ x, unsigned short* __restrict__ xt)
{
    __shared__ unsigned short t[Wn][Cn + 2];
    const int tid = threadIdx.x;
    const int bh  = blockIdx.x;          // b*128 + h
    const int b   = bh >> 7, h = bh & 127;
    const float* xp = x + (((size_t)b*Cn) << 14) + h*Wn;  // xp[c*HWn + w]
    for (int i = tid; i < Cn*Wn; i += 256) {
        int c = i >> 7, w = i & 127;
        t[w][c] = f2bf_hw(xp[(size_t)c*HWn + w]);
    }
    __syncthreads();
    unsigned* xto = (unsigned*)(xt + ((size_t)bh << 7) * Cn);
    for (int j = tid; j < Wn*(Cn/2); j += 256) {
        int w = j >> 6, cp = j & 63;
        xto[(size_t)w*64 + cp] = *(const unsigned*)&t[w][2*cp];
    }
}

// ---------------------------------------------------------------------------
// Kernel 2a: pack deform weights into MFMA A-fragment layout, bf16.
// K-step ks = cchunk*9 + tap (CCHUNK-MAJOR, matches k_deform_mfma).
// Within step: c = cchunk*32 + (l>>4)*8 + j.  Frag blob[ks*8 + ot]:
// lane l elem j -> oc = ot*16 + (l&15).
// ---------------------------------------------------------------------------
__global__ __launch_bounds__(64) void k_pack_w(
    const float* __restrict__ dw, short* __restrict__ pw)
{
    const int blk = blockIdx.x;          // 0..287  (ks*8 + ot)
    const int ks  = blk >> 3;
    const int ot  = blk & 7;
    const int cchunk = ks / 9;
    const int tap    = ks - cchunk*9;
    const int l   = threadIdx.x;
    const int oc  = ot*16 + (l & 15);
    const int kk0 = (l >> 4)*8;
    bf16x8 fr;
    #pragma unroll
    for (int j = 0; j < 8; ++j) {
        int c = cchunk*32 + kk0 + j;
        fr[j] = (short)f2bf_hw(dw[oc*1152 + c*9 + tap]);
    }
    *(bf16x8*)(pw + ((size_t)blk*64 + l)*8) = fr;
}

// ---------------------------------------------------------------------------
// Kernel 2b: pack offset-conv weights (27 oc, padded to 32), cchunk-major.
// ---------------------------------------------------------------------------
__global__ __launch_bounds__(64) void k_pack_ow(
    const float* __restrict__ ow, short* __restrict__ pwo)
{
    const int blk = blockIdx.x;          // 0..71  (ks*2 + ot)
    const int ks  = blk >> 1;
    const int ot  = blk & 1;
    const int cchunk = ks / 9;
    const int tap    = ks - cchunk*9;
    const int l   = threadIdx.x;
    const int oc  = ot*16 + (l & 15);
    const int kk0 = (l >> 4)*8;
    bf16x8 fr;
    #pragma unroll
    for (int j = 0; j < 8; ++j) {
        int c = cchunk*32 + kk0 + j;
        fr[j] = (oc < 27) ? (short)f2bf_hw(ow[oc*1152 + c*9 + tap]) : (short)0;
    }
    *(bf16x8*)(pwo + ((size_t)blk*64 + l)*8) = fr;
}

// ---------------------------------------------------------------------------
// Kernel 3: offset-predicting conv via MFMA on NHWC-bf16 x (R4 form).
// ---------------------------------------------------------------------------
__global__ __launch_bounds__(256) void k_offset_mfma(
    const unsigned short* __restrict__ xt, const short* __restrict__ pwo,
    const float* __restrict__ ob, float* __restrict__ offs)
{
    const int tid = threadIdx.x;
    const int wid = tid >> 6;
    const int l   = tid & 63;
    const int lm  = l & 15;
    const int lg  = l >> 4;
    const int bid = blockIdx.x;                   // 1024 blocks
    const int wg  = (bid & 7)*128 + (bid >> 3);   // XCD-chunked
    const int p   = wg*64 + wid*16 + lm;
    const int b   = p >> 14;
    const int hw  = p & (HWn - 1);
    const int h   = hw >> 7;
    const int w   = hw & (Wn - 1);

    f32x4 acc[2];
    acc[0] = (f32x4){0.f,0.f,0.f,0.f};
    acc[1] = (f32x4){0.f,0.f,0.f,0.f};
    const int4* apg = (const int4*)pwo;

    #pragma unroll 1
    for (int ks = 0; ks < 36; ++ks) {
        const int cchunk = ks / 9;
        const int tap    = ks - cchunk*9;
        const int y  = h + tap/3 - 1;
        const int xx = w + (tap - (tap/3)*3) - 1;
        const bool ok = (y >= 0) & (y < Hn) & (xx >= 0) & (xx < Wn);
        const int yc  = min(max(y, 0), Hn-1);
        const int xc  = min(max(xx, 0), Wn-1);
        int4 v = *(const int4*)(xt + (((size_t)(b*Hn + yc)*Wn + xc) << 7)
                                   + cchunk*32 + lg*8);
        if (!ok) v = make_int4(0,0,0,0);
        const int4* ap = apg + (size_t)(ks*2)*64 + l;
        acc[0] = __builtin_amdgcn_mfma_f32_16x16x32_bf16(
            __builtin_bit_cast(bf16x8, ap[0]),  __builtin_bit_cast(bf16x8, v), acc[0], 0, 0, 0);
        acc[1] = __builtin_amdgcn_mfma_f32_16x16x32_bf16(
            __builtin_bit_cast(bf16x8, ap[64]), __builtin_bit_cast(bf16x8, v), acc[1], 0, 0, 0);
    }

    #pragma unroll
    for (int ot = 0; ot < 2; ++ot)
        #pragma unroll
        for (int r = 0; r < 4; ++r) {
            int oc = ot*16 + lg*4 + r;
            if (oc < 27) offs[(size_t)p*27 + oc] = acc[ot][r] + ob[oc];
        }
}

// ---------------------------------------------------------------------------
// Kernel 4: deformable conv main pass — R4 inner loop + SPLIT-K over waves.
// Block = 8 waves (512 thr): K-group 0 (waves 0-3) does ks 0..17
// (cchunks 0,1), K-group 1 (waves 4-7) does ks 18..35 (cchunks 2,3), both
// for the same 64 pixels. Doubles waves/SIMD (4 -> 8) to hide latency;
// per-group 16KB LDS double-buffer (32KB/block). Epilogue: group 1 dumps
// acc to LDS (32KB, reuses staging space), group 0 reduces + bias + store.
// ---------------------------------------------------------------------------
__global__ __launch_bounds__(512, 8) void k_deform_mfma(
    const unsigned short* __restrict__ xt, const char* __restrict__ pw,
    const float* __restrict__ db, const float* __restrict__ offs,
    float* __restrict__ out)
{
    __shared__ __align__(16) char a_lds[2][2][8192];   // [group][buf][8KB]
    const int tid  = threadIdx.x;
    const int wid  = tid >> 6;
    const int gid  = wid >> 2;     // K-group
    const int wsub = wid & 3;      // pixel-tile within block
    const int l    = tid & 63;
    const int lm   = l & 15;
    const int lg   = l >> 4;
    const int bid  = blockIdx.x;                  // 1024 blocks
    const int wg   = (bid & 7)*128 + (bid >> 3);  // XCD-chunked
    const int p    = wg*64 + wsub*16 + lm;
    const int b    = p >> 14;
    const int hw   = p & (HWn - 1);
    const int h    = hw >> 7;
    const int w    = hw & (Wn - 1);

    f32x4 acc[8];
    #pragma unroll
    for (int ot = 0; ot < 8; ++ot) acc[ot] = (f32x4){0.f,0.f,0.f,0.f};

    const float* op = offs + (size_t)p * 27;
    const int rowbase = b*Hn;
    const int ks0 = gid*18;

    // group stages its own 8KB step-buffer with its 256 threads
    #define STAGE(ks_, buf_) {                                                  \
        const char* g0 = pw + (size_t)(ks_)*8192 + wsub*1024 + l*16;            \
        async_copy16(g0,        (void*)&a_lds[gid][buf_][wsub*1024]);           \
        async_copy16(g0 + 4096, (void*)&a_lds[gid][buf_][4096 + wsub*1024]);    \
    }

    STAGE(ks0, 0);
    int cur = 0;

    #pragma unroll 1
    for (int s = 0; s < 18; ++s) {
        const int ks     = ks0 + s;
        const int cchunk = ks / 9;
        const int tap    = ks - cchunk*9;
        __syncthreads();                       // both groups' buffers staged
        if (s + 1 < 18) STAGE(ks + 1, cur ^ 1);

        // ---- bilinear metadata for (px, tap) ----
        float dy = op[tap], dx = op[9 + tap], mr = op[18 + tap];
        float m  = 1.0f / (1.0f + __expf(-mr));
        float yf = (float)(h + tap/3 - 1) + dy;
        float xf = (float)(w + (tap - (tap/3)*3) - 1) + dx;
        float y0f = floorf(yf), x0f = floorf(xf);
        int   y0  = (int)y0f,  x0  = (int)x0f;
        float wy = yf - y0f, wx = xf - x0f;
        int yi0 = min(max(y0,     0), Hn-1), yi1 = min(max(y0 + 1, 0), Hn-1);
        int xi0 = min(max(x0,     0), Wn-1), xi1 = min(max(x0 + 1, 0), Wn-1);
        float vy0 = ((y0 >= 0)     & (y0 < Hn))     ? 1.0f : 0.0f;
        float vy1 = ((y0 + 1 >= 0) & (y0 + 1 < Hn)) ? 1.0f : 0.0f;
        float vx0 = ((x0 >= 0)     & (x0 < Wn))     ? 1.0f : 0.0f;
        float vx1 = ((x0 + 1 >= 0) & (x0 + 1 < Wn)) ? 1.0f : 0.0f;
        const float w0_ = m * (1.0f-wy) * (1.0f-wx) * vy0 * vx0;
        const float w1_ = m * (1.0f-wy) * wx        * vy0 * vx1;
        const float w2_ = m * wy        * (1.0f-wx) * vy1 * vx0;
        const float w3_ = m * wy        * wx        * vy1 * vx1;

        // ---- 4 corner loads: channel-contiguous bf16x8 each ----
        const int cb = cchunk*32 + lg*8;
        const uint4 q0 = *(const uint4*)(xt + (((size_t)((rowbase + yi0)*Wn + xi0)) << 7) + cb);
        const uint4 q1 = *(const uint4*)(xt + (((size_t)((rowbase + yi0)*Wn + xi1)) << 7) + cb);
        const uint4 q2 = *(const uint4*)(xt + (((size_t)((rowbase + yi1)*Wn + xi0)) << 7) + cb);
        const uint4 q3 = *(const uint4*)(xt + (((size_t)((rowbase + yi1)*Wn + xi1)) << 7) + cb);

        // ---- combine + repack to bf16 (HW cvt_pk) ----
        unsigned bw[4];
        const unsigned* u0 = (const unsigned*)&q0;
        const unsigned* u1 = (const unsigned*)&q1;
        const unsigned* u2 = (const unsigned*)&q2;
        const unsigned* u3 = (const unsigned*)&q3;
        #pragma unroll
        for (int q = 0; q < 4; ++q) {
            float lo = w0_*bflo(u0[q]) + w1_*bflo(u1[q]) + w2_*bflo(u2[q]) + w3_*bflo(u3[q]);
            float hi = w0_*bfhi(u0[q]) + w1_*bfhi(u1[q]) + w2_*bfhi(u2[q]) + w3_*bfhi(u3[q]);
            bw[q] = pack_bf2(lo, hi);
        }
        int4 bi = make_int4(bw[0], bw[1], bw[2], bw[3]);
        bf16x8 bfrag = __builtin_bit_cast(bf16x8, bi);

        // ---- 8 MFMA from LDS-staged A ----
        #pragma unroll
        for (int ot = 0; ot < 8; ++ot) {
            int4 av = *(const int4*)&a_lds[gid][cur][(ot*64 + l)*16];
            acc[ot] = __builtin_amdgcn_mfma_f32_16x16x32_bf16(
                __builtin_bit_cast(bf16x8, av), bfrag, acc[ot], 0, 0, 0);
        }
        cur ^= 1;
    }
    #undef STAGE

    // ---- split-K reduction: group 1 -> LDS, group 0 adds + bias + store ----
    __syncthreads();                           // all staging/consume done
    float4* red = (float4*)a_lds;              // 4*8*64*16B = 32KB, exact fit
    if (gid == 1) {
        #pragma unroll
        for (int ot = 0; ot < 8; ++ot)
            red[(wsub*8 + ot)*64 + l] = (float4){acc[ot][0], acc[ot][1], acc[ot][2], acc[ot][3]};
    }
    __syncthreads();
    if (gid == 0) {
        #pragma unroll
        for (int ot = 0; ot < 8; ++ot) {
            float4 o2 = red[(wsub*8 + ot)*64 + l];
            #pragma unroll
            for (int r = 0; r < 4; ++r) {
                int oc = ot*16 + lg*4 + r;
                out[((size_t)(b*COn + oc) << 14) + hw] = acc[ot][r] + (&o2.x)[r] + db[oc];
            }
        }
    }
}

extern "C" void kernel_launch(void* const* d_in, const int* in_sizes, int n_in,
                              void* d_out, int out_size, void* d_ws, size_t ws_size,
                              hipStream_t stream) {
    const float* x  = (const float*)d_in[0];
    const float* ow = (const float*)d_in[1];
    const float* ob = (const float*)d_in[2];
    const float* dw = (const float*)d_in[3];
    const float* db = (const float*)d_in[4];
    float* out  = (float*)d_out;

    // workspace layout (24.2 MB total)
    float*          offs = (float*)d_ws;                            // 7,077,888 B
    short*          pw   = (short*)((char*)d_ws + 7077888);         //   294,912 B
    short*          pwo  = (short*)((char*)d_ws + 7372800);         //    73,728 B
    unsigned short* xtp  = (unsigned short*)((char*)d_ws + 7446528);// 16,777,216 B

    hipLaunchKernelGGL(k_transpose,   dim3(Bn*Hn),    dim3(256), 0, stream, x, xtp);
    hipLaunchKernelGGL(k_pack_w,      dim3(288),      dim3(64),  0, stream, dw, pw);
    hipLaunchKernelGGL(k_pack_ow,     dim3(72),       dim3(64),  0, stream, ow, pwo);
    hipLaunchKernelGGL(k_offset_mfma, dim3(NPIX/64),  dim3(256), 0, stream, xtp, pwo, ob, offs);
    hipLaunchKernelGGL(k_deform_mfma, dim3(NPIX/64),  dim3(512), 0, stream,
                       xtp, (const char*)pw, db, offs, out);
}

// Round 7
// 147.524 us; speedup vs baseline: 1.2513x; 1.2513x over previous
//
#include <hip/hip_runtime.h>
#include <hip/hip_bf16.h>
#include <math.h>

#define Bn 4
#define Cn 128
#define Hn 128
#define Wn 128
#define COn 128
#define HWn (Hn*Wn)        // 16384
#define NPIX (Bn*HWn)      // 65536

typedef __attribute__((ext_vector_type(8))) short bf16x8;
typedef __attribute__((ext_vector_type(4))) float f32x4;

__device__ inline unsigned short f2bf_hw(float f) {
    __hip_bfloat16 h = __float2bfloat16(f);     // HW cvt (RNE)
    return *reinterpret_cast<unsigned short*>(&h);
}
__device__ inline unsigned pack_bf2(float lo, float hi) {
    __hip_bfloat162 h2;
    h2.x = __float2bfloat16(lo);
    h2.y = __float2bfloat16(hi);                // fuses to v_cvt_pk_bf16_f32
    return *reinterpret_cast<unsigned*>(&h2);
}
__device__ inline float bflo(unsigned w) {
    union { unsigned u; float f; } cv; cv.u = w << 16; return cv.f;
}
__device__ inline float bfhi(unsigned w) {
    union { unsigned u; float f; } cv; cv.u = w & 0xffff0000u; return cv.f;
}
__device__ inline void async_copy16(const void* g, void* l) {
    __builtin_amdgcn_global_load_lds(
        (const __attribute__((address_space(1))) unsigned int*)g,
        (__attribute__((address_space(3))) unsigned int*)l, 16, 0, 0);
}

// ---------------------------------------------------------------------------
// Kernel 1: NCHW f32 -> NHWC bf16 transpose. Block = one (b,h) row.
// ---------------------------------------------------------------------------
__global__ __launch_bounds__(256) void k_transpose(
    const float* __restrict__ x, unsigned short* __restrict__ xt)
{
    __shared__ unsigned short t[Wn][Cn + 2];
    const int tid = threadIdx.x;
    const int bh  = blockIdx.x;          // b*128 + h
    const int b   = bh >> 7, h = bh & 127;
    const float* xp = x + (((size_t)b*Cn) << 14) + h*Wn;  // xp[c*HWn + w]
    for (int i = tid; i < Cn*Wn; i += 256) {
        int c = i >> 7, w = i & 127;
        t[w][c] = f2bf_hw(xp[(size_t)c*HWn + w]);
    }
    __syncthreads();
    unsigned* xto = (unsigned*)(xt + ((size_t)bh << 7) * Cn);
    for (int j = tid; j < Wn*(Cn/2); j += 256) {
        int w = j >> 6, cp = j & 63;
        xto[(size_t)w*64 + cp] = *(const unsigned*)&t[w][2*cp];
    }
}

// ---------------------------------------------------------------------------
// Kernel 2a: pack deform weights into MFMA A-fragment layout, bf16.
// K-step ks = cchunk*9 + tap (CCHUNK-MAJOR, matches k_deform_mfma).
// Within step: c = cchunk*32 + (l>>4)*8 + j.  Frag blob[ks*8 + ot]:
// lane l elem j -> oc = ot*16 + (l&15).
// ---------------------------------------------------------------------------
__global__ __launch_bounds__(64) void k_pack_w(
    const float* __restrict__ dw, short* __restrict__ pw)
{
    const int blk = blockIdx.x;          // 0..287  (ks*8 + ot)
    const int ks  = blk >> 3;
    const int ot  = blk & 7;
    const int cchunk = ks / 9;
    const int tap    = ks - cchunk*9;
    const int l   = threadIdx.x;
    const int oc  = ot*16 + (l & 15);
    const int kk0 = (l >> 4)*8;
    bf16x8 fr;
    #pragma unroll
    for (int j = 0; j < 8; ++j) {
        int c = cchunk*32 + kk0 + j;
        fr[j] = (short)f2bf_hw(dw[oc*1152 + c*9 + tap]);
    }
    *(bf16x8*)(pw + ((size_t)blk*64 + l)*8) = fr;
}

// ---------------------------------------------------------------------------
// Kernel 2b: pack offset-conv weights (27 oc, padded to 32), cchunk-major.
// ---------------------------------------------------------------------------
__global__ __launch_bounds__(64) void k_pack_ow(
    const float* __restrict__ ow, short* __restrict__ pwo)
{
    const int blk = blockIdx.x;          // 0..71  (ks*2 + ot)
    const int ks  = blk >> 1;
    const int ot  = blk & 1;
    const int cchunk = ks / 9;
    const int tap    = ks - cchunk*9;
    const int l   = threadIdx.x;
    const int oc  = ot*16 + (l & 15);
    const int kk0 = (l >> 4)*8;
    bf16x8 fr;
    #pragma unroll
    for (int j = 0; j < 8; ++j) {
        int c = cchunk*32 + kk0 + j;
        fr[j] = (oc < 27) ? (short)f2bf_hw(ow[oc*1152 + c*9 + tap]) : (short)0;
    }
    *(bf16x8*)(pwo + ((size_t)blk*64 + l)*8) = fr;
}

// ---------------------------------------------------------------------------
// Kernel 3: offset-predicting conv via MFMA on NHWC-bf16 x (R4 form).
// ---------------------------------------------------------------------------
__global__ __launch_bounds__(256) void k_offset_mfma(
    const unsigned short* __restrict__ xt, const short* __restrict__ pwo,
    const float* __restrict__ ob, float* __restrict__ offs)
{
    const int tid = threadIdx.x;
    const int wid = tid >> 6;
    const int l   = tid & 63;
    const int lm  = l & 15;
    const int lg  = l >> 4;
    const int bid = blockIdx.x;                   // 1024 blocks
    const int wg  = (bid & 7)*128 + (bid >> 3);   // XCD-chunked
    const int p   = wg*64 + wid*16 + lm;
    const int b   = p >> 14;
    const int hw  = p & (HWn - 1);
    const int h   = hw >> 7;
    const int w   = hw & (Wn - 1);

    f32x4 acc[2];
    acc[0] = (f32x4){0.f,0.f,0.f,0.f};
    acc[1] = (f32x4){0.f,0.f,0.f,0.f};
    const int4* apg = (const int4*)pwo;

    #pragma unroll 1
    for (int ks = 0; ks < 36; ++ks) {
        const int cchunk = ks / 9;
        const int tap    = ks - cchunk*9;
        const int y  = h + tap/3 - 1;
        const int xx = w + (tap - (tap/3)*3) - 1;
        const bool ok = (y >= 0) & (y < Hn) & (xx >= 0) & (xx < Wn);
        const int yc  = min(max(y, 0), Hn-1);
        const int xc  = min(max(xx, 0), Wn-1);
        int4 v = *(const int4*)(xt + (((size_t)(b*Hn + yc)*Wn + xc) << 7)
                                   + cchunk*32 + lg*8);
        if (!ok) v = make_int4(0,0,0,0);
        const int4* ap = apg + (size_t)(ks*2)*64 + l;
        acc[0] = __builtin_amdgcn_mfma_f32_16x16x32_bf16(
            __builtin_bit_cast(bf16x8, ap[0]),  __builtin_bit_cast(bf16x8, v), acc[0], 0, 0, 0);
        acc[1] = __builtin_amdgcn_mfma_f32_16x16x32_bf16(
            __builtin_bit_cast(bf16x8, ap[64]), __builtin_bit_cast(bf16x8, v), acc[1], 0, 0, 0);
    }

    #pragma unroll
    for (int ot = 0; ot < 2; ++ot)
        #pragma unroll
        for (int r = 0; r < 4; ++r) {
            int oc = ot*16 + lg*4 + r;
            if (oc < 27) offs[(size_t)p*27 + oc] = acc[ot][r] + ob[oc];
        }
}

// ---------------------------------------------------------------------------
// Kernel 4: deformable conv main pass — R4 inner loop + 2-way SPLIT-K,
// 256-thread blocks (4 waves = 2 px-tiles x 2 K-groups, 32 px/block).
// Waves 0,1: px-tiles 0,1 with ks 0..17; waves 2,3: same tiles, ks 18..35.
// Grid 2048 -> 8192 waves total (2x R4). Natural regs ~92 -> 5 waves/SIMD;
// LDS 32KB/block -> 5 blocks/CU = 160KB exact. launch_bounds(256,5) caps
// at 102 regs (>natural, no spill — R6's mistake was 64 < natural).
// Epilogue: K-group 1 dumps acc to LDS (16KB, reuses staging), group 0
// reduces + bias + store.
// ---------------------------------------------------------------------------
__global__ __launch_bounds__(256, 5) void k_deform_mfma(
    const unsigned short* __restrict__ xt, const char* __restrict__ pw,
    const float* __restrict__ db, const float* __restrict__ offs,
    float* __restrict__ out)
{
    __shared__ __align__(16) char a_lds[2][2][8192];   // [group][buf][8KB]
    const int tid  = threadIdx.x;
    const int wid  = tid >> 6;
    const int gid  = wid >> 1;     // K-group (0: ks 0-17, 1: ks 18-35)
    const int wsub = wid & 1;      // pixel-tile within block
    const int l    = tid & 63;
    const int lm   = l & 15;
    const int lg   = l >> 4;
    const int bid  = blockIdx.x;                  // 2048 blocks, %8==0
    const int wg   = (bid & 7)*256 + (bid >> 3);  // XCD-chunked (bijective)
    const int p    = wg*32 + wsub*16 + lm;
    const int b    = p >> 14;
    const int hw   = p & (HWn - 1);
    const int h    = hw >> 7;
    const int w    = hw & (Wn - 1);

    f32x4 acc[8];
    #pragma unroll
    for (int ot = 0; ot < 8; ++ot) acc[ot] = (f32x4){0.f,0.f,0.f,0.f};

    const float* op = offs + (size_t)p * 27;
    const int rowbase = b*Hn;
    const int ks0 = gid*18;

    // group = 2 waves (128 threads); 8KB staged as 4 wave-uniform 1KB chunks
    // per wave: lds dest base uniform, lane*16 offsets (global_load_lds rule).
    #define STAGE(ks_, buf_) {                                                  \
        const char* g0 = pw + (size_t)(ks_)*8192 + wsub*1024 + l*16;            \
        async_copy16(g0,        (void*)&a_lds[gid][buf_][wsub*1024]);           \
        async_copy16(g0 + 2048, (void*)&a_lds[gid][buf_][wsub*1024 + 2048]);    \
        async_copy16(g0 + 4096, (void*)&a_lds[gid][buf_][wsub*1024 + 4096]);    \
        async_copy16(g0 + 6144, (void*)&a_lds[gid][buf_][wsub*1024 + 6144]);    \
    }

    STAGE(ks0, 0);
    int cur = 0;

    #pragma unroll 1
    for (int s = 0; s < 18; ++s) {
        const int ks     = ks0 + s;
        const int cchunk = ks / 9;
        const int tap    = ks - cchunk*9;
        __syncthreads();                       // both groups' buffers staged
        if (s + 1 < 18) STAGE(ks0 + s + 1, cur ^ 1);

        // ---- bilinear metadata for (px, tap) ----
        float dy = op[tap], dx = op[9 + tap], mr = op[18 + tap];
        float m  = 1.0f / (1.0f + __expf(-mr));
        float yf = (float)(h + tap/3 - 1) + dy;
        float xf = (float)(w + (tap - (tap/3)*3) - 1) + dx;
        float y0f = floorf(yf), x0f = floorf(xf);
        int   y0  = (int)y0f,  x0  = (int)x0f;
        float wy = yf - y0f, wx = xf - x0f;
        int yi0 = min(max(y0,     0), Hn-1), yi1 = min(max(y0 + 1, 0), Hn-1);
        int xi0 = min(max(x0,     0), Wn-1), xi1 = min(max(x0 + 1, 0), Wn-1);
        float vy0 = ((y0 >= 0)     & (y0 < Hn))     ? 1.0f : 0.0f;
        float vy1 = ((y0 + 1 >= 0) & (y0 + 1 < Hn)) ? 1.0f : 0.0f;
        float vx0 = ((x0 >= 0)     & (x0 < Wn))     ? 1.0f : 0.0f;
        float vx1 = ((x0 + 1 >= 0) & (x0 + 1 < Wn)) ? 1.0f : 0.0f;
        const float w0_ = m * (1.0f-wy) * (1.0f-wx) * vy0 * vx0;
        const float w1_ = m * (1.0f-wy) * wx        * vy0 * vx1;
        const float w2_ = m * wy        * (1.0f-wx) * vy1 * vx0;
        const float w3_ = m * wy        * wx        * vy1 * vx1;

        // ---- 4 corner loads: channel-contiguous bf16x8 each ----
        const int cb = cchunk*32 + lg*8;
        const uint4 q0 = *(const uint4*)(xt + (((size_t)((rowbase + yi0)*Wn + xi0)) << 7) + cb);
        const uint4 q1 = *(const uint4*)(xt + (((size_t)((rowbase + yi0)*Wn + xi1)) << 7) + cb);
        const uint4 q2 = *(const uint4*)(xt + (((size_t)((rowbase + yi1)*Wn + xi0)) << 7) + cb);
        const uint4 q3 = *(const uint4*)(xt + (((size_t)((rowbase + yi1)*Wn + xi1)) << 7) + cb);

        // ---- combine + repack to bf16 (HW cvt_pk) ----
        unsigned bw[4];
        const unsigned* u0 = (const unsigned*)&q0;
        const unsigned* u1 = (const unsigned*)&q1;
        const unsigned* u2 = (const unsigned*)&q2;
        const unsigned* u3 = (const unsigned*)&q3;
        #pragma unroll
        for (int q = 0; q < 4; ++q) {
            float lo = w0_*bflo(u0[q]) + w1_*bflo(u1[q]) + w2_*bflo(u2[q]) + w3_*bflo(u3[q]);
            float hi = w0_*bfhi(u0[q]) + w1_*bfhi(u1[q]) + w2_*bfhi(u2[q]) + w3_*bfhi(u3[q]);
            bw[q] = pack_bf2(lo, hi);
        }
        int4 bi = make_int4(bw[0], bw[1], bw[2], bw[3]);
        bf16x8 bfrag = __builtin_bit_cast(bf16x8, bi);

        // ---- 8 MFMA from LDS-staged A ----
        #pragma unroll
        for (int ot = 0; ot < 8; ++ot) {
            int4 av = *(const int4*)&a_lds[gid][cur][(ot*64 + l)*16];
            acc[ot] = __builtin_amdgcn_mfma_f32_16x16x32_bf16(
                __builtin_bit_cast(bf16x8, av), bfrag, acc[ot], 0, 0, 0);
        }
        cur ^= 1;
    }
    #undef STAGE

    // ---- split-K reduction: group 1 -> LDS, group 0 adds + bias + store ----
    __syncthreads();                           // all staging/consume done
    float4* red = (float4*)a_lds;              // 2*8*64*16B = 16KB used
    if (gid == 1) {
        #pragma unroll
        for (int ot = 0; ot < 8; ++ot)
            red[(wsub*8 + ot)*64 + l] = (float4){acc[ot][0], acc[ot][1], acc[ot][2], acc[ot][3]};
    }
    __syncthreads();
    if (gid == 0) {
        #pragma unroll
        for (int ot = 0; ot < 8; ++ot) {
            float4 o2 = red[(wsub*8 + ot)*64 + l];
            #pragma unroll
            for (int r = 0; r < 4; ++r) {
                int oc = ot*16 + lg*4 + r;
                out[((size_t)(b*COn + oc) << 14) + hw] = acc[ot][r] + (&o2.x)[r] + db[oc];
            }
        }
    }
}

extern "C" void kernel_launch(void* const* d_in, const int* in_sizes, int n_in,
                              void* d_out, int out_size, void* d_ws, size_t ws_size,
                              hipStream_t stream) {
    const float* x  = (const float*)d_in[0];
    const float* ow = (const float*)d_in[1];
    const float* ob = (const float*)d_in[2];
    const float* dw = (const float*)d_in[3];
    const float* db = (const float*)d_in[4];
    float* out  = (float*)d_out;

    // workspace layout (24.2 MB total)
    float*          offs = (float*)d_ws;                            // 7,077,888 B
    short*          pw   = (short*)((char*)d_ws + 7077888);         //   294,912 B
    short*          pwo  = (short*)((char*)d_ws + 7372800);         //    73,728 B
    unsigned short* xtp  = (unsigned short*)((char*)d_ws + 7446528);// 16,777,216 B

    hipLaunchKernelGGL(k_transpose,   dim3(Bn*Hn),    dim3(256), 0, stream, x, xtp);
    hipLaunchKernelGGL(k_pack_w,      dim3(288),      dim3(64),  0, stream, dw, pw);
    hipLaunchKernelGGL(k_pack_ow,     dim3(72),       dim3(64),  0, stream, ow, pwo);
    hipLaunchKernelGGL(k_offset_mfma, dim3(NPIX/64),  dim3(256), 0, stream, xtp, pwo, ob, offs);
    hipLaunchKernelGGL(k_deform_mfma, dim3(NPIX/32),  dim3(256), 0, stream,
                       xtp, (const char*)pw, db, offs, out);
}

// Round 8
// 124.420 us; speedup vs baseline: 1.4836x; 1.1857x over previous
//
#include <hip/hip_runtime.h>
#include <hip/hip_bf16.h>
#include <math.h>

#define Bn 4
#define Cn 128
#define Hn 128
#define Wn 128
#define COn 128
#define HWn (Hn*Wn)        // 16384
#define NPIX (Bn*HWn)      // 65536

typedef __attribute__((ext_vector_type(8))) short bf16x8;
typedef __attribute__((ext_vector_type(4))) float f32x4;

__device__ inline unsigned short f2bf_hw(float f) {
    __hip_bfloat16 h = __float2bfloat16(f);     // HW cvt (RNE)
    return *reinterpret_cast<unsigned short*>(&h);
}
__device__ inline unsigned pack_bf2(float lo, float hi) {
    __hip_bfloat162 h2;
    h2.x = __float2bfloat16(lo);
    h2.y = __float2bfloat16(hi);                // fuses to v_cvt_pk_bf16_f32
    return *reinterpret_cast<unsigned*>(&h2);
}
__device__ inline float bflo(unsigned w) {
    union { unsigned u; float f; } cv; cv.u = w << 16; return cv.f;
}
__device__ inline float bfhi(unsigned w) {
    union { unsigned u; float f; } cv; cv.u = w & 0xffff0000u; return cv.f;
}
__device__ inline void async_copy16(const void* g, void* l) {
    __builtin_amdgcn_global_load_lds(
        (const __attribute__((address_space(1))) unsigned int*)g,
        (__attribute__((address_space(3))) unsigned int*)l, 16, 0, 0);
}

// ---------------------------------------------------------------------------
// Kernel 1: NCHW f32 -> NHWC bf16 transpose. Block = one (b,h) row.
// ---------------------------------------------------------------------------
__global__ __launch_bounds__(256) void k_transpose(
    const float* __restrict__ x, unsigned short* __restrict__ xt)
{
    __shared__ unsigned short t[Wn][Cn + 2];
    const int tid = threadIdx.x;
    const int bh  = blockIdx.x;          // b*128 + h
    const int b   = bh >> 7, h = bh & 127;
    const float* xp = x + (((size_t)b*Cn) << 14) + h*Wn;  // xp[c*HWn + w]
    for (int i = tid; i < Cn*Wn; i += 256) {
        int c = i >> 7, w = i & 127;
        t[w][c] = f2bf_hw(xp[(size_t)c*HWn + w]);
    }
    __syncthreads();
    unsigned* xto = (unsigned*)(xt + ((size_t)bh << 7) * Cn);
    for (int j = tid; j < Wn*(Cn/2); j += 256) {
        int w = j >> 6, cp = j & 63;
        xto[(size_t)w*64 + cp] = *(const unsigned*)&t[w][2*cp];
    }
}

// ---------------------------------------------------------------------------
// Kernel 2a: pack deform weights into MFMA A-fragment layout, bf16.
// K-step ks = cchunk*9 + tap (CCHUNK-MAJOR, matches k_deform_mfma).
// ---------------------------------------------------------------------------
__global__ __launch_bounds__(64) void k_pack_w(
    const float* __restrict__ dw, short* __restrict__ pw)
{
    const int blk = blockIdx.x;          // 0..287  (ks*8 + ot)
    const int ks  = blk >> 3;
    const int ot  = blk & 7;
    const int cchunk = ks / 9;
    const int tap    = ks - cchunk*9;
    const int l   = threadIdx.x;
    const int oc  = ot*16 + (l & 15);
    const int kk0 = (l >> 4)*8;
    bf16x8 fr;
    #pragma unroll
    for (int j = 0; j < 8; ++j) {
        int c = cchunk*32 + kk0 + j;
        fr[j] = (short)f2bf_hw(dw[oc*1152 + c*9 + tap]);
    }
    *(bf16x8*)(pw + ((size_t)blk*64 + l)*8) = fr;
}

// ---------------------------------------------------------------------------
// Kernel 2b: pack offset-conv weights (27 oc, padded to 32), cchunk-major.
// ---------------------------------------------------------------------------
__global__ __launch_bounds__(64) void k_pack_ow(
    const float* __restrict__ ow, short* __restrict__ pwo)
{
    const int blk = blockIdx.x;          // 0..71  (ks*2 + ot)
    const int ks  = blk >> 1;
    const int ot  = blk & 1;
    const int cchunk = ks / 9;
    const int tap    = ks - cchunk*9;
    const int l   = threadIdx.x;
    const int oc  = ot*16 + (l & 15);
    const int kk0 = (l >> 4)*8;
    bf16x8 fr;
    #pragma unroll
    for (int j = 0; j < 8; ++j) {
        int c = cchunk*32 + kk0 + j;
        fr[j] = (oc < 27) ? (short)f2bf_hw(ow[oc*1152 + c*9 + tap]) : (short)0;
    }
    *(bf16x8*)(pwo + ((size_t)blk*64 + l)*8) = fr;
}

// ---------------------------------------------------------------------------
// Kernel 3: offset conv via MFMA + FUSED gather-metadata epilogue.
// After the 36 K-step MFMA loop, each wave dumps its 16px x 32oc results to
// LDS (pad 33 vs bank conflicts), then lanes compute 144 (tap,px) metadata
// records: {off0 bytes (incl batch), flags (dx=256|dy=32768), 4 bf16 combined
// weights = mask*valid*bilinear}. Stored meta[tap*NPIX + p], 16B each.
// ---------------------------------------------------------------------------
__global__ __launch_bounds__(256) void k_offset_mfma(
    const unsigned short* __restrict__ xt, const short* __restrict__ pwo,
    const float* __restrict__ ob, uint4* __restrict__ meta)
{
    __shared__ float ol[4][16][33];     // 8448 B
    const int tid = threadIdx.x;
    const int wid = tid >> 6;
    const int l   = tid & 63;
    const int lm  = l & 15;
    const int lg  = l >> 4;
    const int bid = blockIdx.x;                   // 1024 blocks
    const int wg  = (bid & 7)*128 + (bid >> 3);   // XCD-chunked
    const int p   = wg*64 + wid*16 + lm;
    const int b   = p >> 14;
    const int hw  = p & (HWn - 1);
    const int h   = hw >> 7;
    const int w   = hw & (Wn - 1);

    f32x4 acc[2];
    acc[0] = (f32x4){0.f,0.f,0.f,0.f};
    acc[1] = (f32x4){0.f,0.f,0.f,0.f};
    const int4* apg = (const int4*)pwo;

    #pragma unroll 1
    for (int ks = 0; ks < 36; ++ks) {
        const int cchunk = ks / 9;
        const int tap    = ks - cchunk*9;
        const int y  = h + tap/3 - 1;
        const int xx = w + (tap - (tap/3)*3) - 1;
        const bool ok = (y >= 0) & (y < Hn) & (xx >= 0) & (xx < Wn);
        const int yc  = min(max(y, 0), Hn-1);
        const int xc  = min(max(xx, 0), Wn-1);
        int4 v = *(const int4*)(xt + (((size_t)(b*Hn + yc)*Wn + xc) << 7)
                                   + cchunk*32 + lg*8);
        if (!ok) v = make_int4(0,0,0,0);
        const int4* ap = apg + (size_t)(ks*2)*64 + l;
        acc[0] = __builtin_amdgcn_mfma_f32_16x16x32_bf16(
            __builtin_bit_cast(bf16x8, ap[0]),  __builtin_bit_cast(bf16x8, v), acc[0], 0, 0, 0);
        acc[1] = __builtin_amdgcn_mfma_f32_16x16x32_bf16(
            __builtin_bit_cast(bf16x8, ap[64]), __builtin_bit_cast(bf16x8, v), acc[1], 0, 0, 0);
    }

    // ---- dump offsets (+bias) to LDS: [wid][px][oc] ----
    #pragma unroll
    for (int ot = 0; ot < 2; ++ot)
        #pragma unroll
        for (int r = 0; r < 4; ++r) {
            int oc = ot*16 + lg*4 + r;
            ol[wid][lm][oc] = acc[ot][r] + ((oc < 27) ? ob[oc] : 0.0f);
        }
    // same-wave ds_write -> ds_read: compiler inserts lgkmcnt wait

    // ---- metadata for the wave's 16 pixels x 9 taps ----
    const int pbase = wg*64 + wid*16;
    for (int i = l; i < 144; i += 64) {
        const int tap = i >> 4;
        const int px  = i & 15;
        const int pp  = pbase + px;
        const int bb  = pp >> 14;
        const int hh  = (pp & (HWn-1)) >> 7;
        const int ww  = pp & 127;
        float dy = ol[wid][px][tap];
        float dx = ol[wid][px][9 + tap];
        float mr = ol[wid][px][18 + tap];
        float m  = 1.0f / (1.0f + __expf(-mr));
        float yf = (float)(hh + tap/3 - 1) + dy;
        float xf = (float)(ww + (tap - (tap/3)*3) - 1) + dx;
        float y0f = floorf(yf), x0f = floorf(xf);
        int   y0  = (int)y0f,  x0  = (int)x0f;
        float wy = yf - y0f, wx = xf - x0f;
        int yi0 = min(max(y0,     0), Hn-1), yi1 = min(max(y0 + 1, 0), Hn-1);
        int xi0 = min(max(x0,     0), Wn-1), xi1 = min(max(x0 + 1, 0), Wn-1);
        float vy0 = ((y0 >= 0)     & (y0 < Hn))     ? 1.0f : 0.0f;
        float vy1 = ((y0 + 1 >= 0) & (y0 + 1 < Hn)) ? 1.0f : 0.0f;
        float vx0 = ((x0 >= 0)     & (x0 < Wn))     ? 1.0f : 0.0f;
        float vx1 = ((x0 + 1 >= 0) & (x0 + 1 < Wn)) ? 1.0f : 0.0f;
        float w0_ = m * (1.0f-wy) * (1.0f-wx) * vy0 * vx0;
        float w1_ = m * (1.0f-wy) * wx        * vy0 * vx1;
        float w2_ = m * wy        * (1.0f-wx) * vy1 * vx0;
        float w3_ = m * wy        * wx        * vy1 * vx1;
        uint4 mq;
        mq.x = (unsigned)(((bb << 14) + yi0*Wn + xi0) << 8);   // byte offset
        mq.y = (unsigned)((xi1 - xi0)*256) | (unsigned)((yi1 - yi0)*32768);
        mq.z = pack_bf2(w0_, w1_);
        mq.w = pack_bf2(w2_, w3_);
        meta[(size_t)tap*NPIX + pp] = mq;
    }
}

// ---------------------------------------------------------------------------
// Kernel 4: deformable conv main pass — R4 structure (1024 blocks, 4 waves,
// 16 px/wave, 16KB rolling LDS dbuf for A) with PRECOMPUTED gather metadata:
// per K-step = 1x 16B meta load + 3 int adds + 4 corner dwordx4 + combine
// + 8 MFMA. No sigmoid/floor/clamp chain in the hot loop.
// ---------------------------------------------------------------------------
__global__ __launch_bounds__(256) void k_deform_mfma(
    const unsigned short* __restrict__ xt, const char* __restrict__ pw,
    const float* __restrict__ db, const uint4* __restrict__ meta,
    float* __restrict__ out)
{
    __shared__ __align__(16) char a_lds[2][8192];
    const int tid = threadIdx.x;
    const int wid = tid >> 6;
    const int l   = tid & 63;
    const int lm  = l & 15;
    const int lg  = l >> 4;
    const int bid = blockIdx.x;                   // 1024 blocks
    const int wg  = (bid & 7)*128 + (bid >> 3);   // XCD-chunked
    const int p   = wg*64 + wid*16 + lm;
    const int b   = p >> 14;
    const int hw  = p & (HWn - 1);

    f32x4 acc[8];
    #pragma unroll
    for (int ot = 0; ot < 8; ++ot) acc[ot] = (f32x4){0.f,0.f,0.f,0.f};

    const uint4* mbase = meta + p;
    const char*  xb    = (const char*)xt;

    #define STAGE(ks_, buf_) {                                                  \
        const char* g0 = pw + (size_t)(ks_)*8192 + wid*1024 + l*16;             \
        async_copy16(g0,        (void*)&a_lds[buf_][wid*1024]);                 \
        async_copy16(g0 + 4096, (void*)&a_lds[buf_][4096 + wid*1024]);          \
    }

    STAGE(0, 0);
    int cur = 0;

    #pragma unroll 1
    for (int ks = 0; ks < 36; ++ks) {
        const int cchunk = ks / 9;
        const int tap    = ks - cchunk*9;
        __syncthreads();                       // buf[cur] staged for all waves
        if (ks + 1 < 36) STAGE(ks + 1, cur ^ 1);

        // ---- metadata: one 16B load, broadcast across lg groups ----
        const uint4 mq = mbase[(size_t)tap*NPIX];
        const unsigned offc = mq.x + (unsigned)(cchunk*64 + lg*16);
        const unsigned dxb  = mq.y & 256u;
        const unsigned dyb  = mq.y & 32768u;

        const uint4 q0 = *(const uint4*)(xb + offc);
        const uint4 q1 = *(const uint4*)(xb + (offc + dxb));
        const uint4 q2 = *(const uint4*)(xb + (offc + dyb));
        const uint4 q3 = *(const uint4*)(xb + (offc + dyb + dxb));

        const float w0_ = bflo(mq.z), w1_ = bfhi(mq.z);
        const float w2_ = bflo(mq.w), w3_ = bfhi(mq.w);

        // ---- combine + repack to bf16 (HW cvt_pk) ----
        unsigned bw[4];
        const unsigned* u0 = (const unsigned*)&q0;
        const unsigned* u1 = (const unsigned*)&q1;
        const unsigned* u2 = (const unsigned*)&q2;
        const unsigned* u3 = (const unsigned*)&q3;
        #pragma unroll
        for (int q = 0; q < 4; ++q) {
            float lo = w0_*bflo(u0[q]) + w1_*bflo(u1[q]) + w2_*bflo(u2[q]) + w3_*bflo(u3[q]);
            float hi = w0_*bfhi(u0[q]) + w1_*bfhi(u1[q]) + w2_*bfhi(u2[q]) + w3_*bfhi(u3[q]);
            bw[q] = pack_bf2(lo, hi);
        }
        int4 bi = make_int4(bw[0], bw[1], bw[2], bw[3]);
        bf16x8 bfrag = __builtin_bit_cast(bf16x8, bi);

        // ---- 8 MFMA from LDS-staged A ----
        #pragma unroll
        for (int ot = 0; ot < 8; ++ot) {
            int4 av = *(const int4*)&a_lds[cur][(ot*64 + l)*16];
            acc[ot] = __builtin_amdgcn_mfma_f32_16x16x32_bf16(
                __builtin_bit_cast(bf16x8, av), bfrag, acc[ot], 0, 0, 0);
        }
        cur ^= 1;
    }
    #undef STAGE

    // ---- epilogue ----
    #pragma unroll
    for (int ot = 0; ot < 8; ++ot) {
        #pragma unroll
        for (int r = 0; r < 4; ++r) {
            int oc = ot*16 + lg*4 + r;
            out[((size_t)(b*COn + oc) << 14) + hw] = acc[ot][r] + db[oc];
        }
    }
}

extern "C" void kernel_launch(void* const* d_in, const int* in_sizes, int n_in,
                              void* d_out, int out_size, void* d_ws, size_t ws_size,
                              hipStream_t stream) {
    const float* x  = (const float*)d_in[0];
    const float* ow = (const float*)d_in[1];
    const float* ob = (const float*)d_in[2];
    const float* dw = (const float*)d_in[3];
    const float* db = (const float*)d_in[4];
    float* out  = (float*)d_out;

    // workspace layout (26.6 MB total)
    uint4*          meta = (uint4*)d_ws;                            // 9,437,184 B
    short*          pw   = (short*)((char*)d_ws + 9437184);         //   294,912 B
    short*          pwo  = (short*)((char*)d_ws + 9732096);         //    73,728 B
    unsigned short* xtp  = (unsigned short*)((char*)d_ws + 9805824);// 16,777,216 B

    hipLaunchKernelGGL(k_transpose,   dim3(Bn*Hn),    dim3(256), 0, stream, x, xtp);
    hipLaunchKernelGGL(k_pack_w,      dim3(288),      dim3(64),  0, stream, dw, pw);
    hipLaunchKernelGGL(k_pack_ow,     dim3(72),       dim3(64),  0, stream, ow, pwo);
    hipLaunchKernelGGL(k_offset_mfma, dim3(NPIX/64),  dim3(256), 0, stream, xtp, pwo, ob, meta);
    hipLaunchKernelGGL(k_deform_mfma, dim3(NPIX/64),  dim3(256), 0, stream,
                       xtp, (const char*)pw, db, meta, out);
}